// Round 1
// baseline (2451.219 us; speedup 1.0000x reference)
//
#include <hip/hip_runtime.h>

#define N_USERS 100000
#define N_ITEMS 150000
#define N_REL 16
#define N_FACT 4
#define DD 64
#define N_EDGES 2000000
#define NNZ 2000000

// ---------------- cor (tiny, single thread) ----------------
__global__ void cor_kernel(const float* __restrict__ att, float* __restrict__ cor_out) {
    if (threadIdx.x != 0 || blockIdx.x != 0) return;
    float cor = 0.f;
    for (int i = 0; i < N_FACT; ++i) {
        for (int j = i + 1; j < N_FACT; ++j) {
            const float* t1 = att + i * N_REL;
            const float* t2 = att + j * N_REL;
            float rowx[16], colx[16], rowy[16], coly[16];
            for (int a = 0; a < 16; ++a) { rowx[a]=0.f; colx[a]=0.f; rowy[a]=0.f; coly[a]=0.f; }
            float totx = 0.f, toty = 0.f;
            for (int a = 0; a < 16; ++a) {
                for (int b = 0; b < 16; ++b) {
                    float dx = sqrtf(fmaxf(t1[a]*t1[a] - 2.f*t1[a]*t1[b] + t1[b]*t1[b], 0.f) + 1e-8f);
                    float dy = sqrtf(fmaxf(t2[a]*t2[a] - 2.f*t2[a]*t2[b] + t2[b]*t2[b], 0.f) + 1e-8f);
                    rowx[a] += dx; colx[b] += dx; totx += dx;
                    rowy[a] += dy; coly[b] += dy; toty += dy;
                }
            }
            float sAB = 0.f, sAA = 0.f, sBB = 0.f;
            for (int a = 0; a < 16; ++a) {
                for (int b = 0; b < 16; ++b) {
                    float dx = sqrtf(fmaxf(t1[a]*t1[a] - 2.f*t1[a]*t1[b] + t1[b]*t1[b], 0.f) + 1e-8f);
                    float dy = sqrtf(fmaxf(t2[a]*t2[a] - 2.f*t2[a]*t2[b] + t2[b]*t2[b], 0.f) + 1e-8f);
                    float A = dx - colx[b]*(1.f/16.f) - rowx[a]*(1.f/16.f) + totx*(1.f/256.f);
                    float B = dy - coly[b]*(1.f/16.f) - rowy[a]*(1.f/16.f) + toty*(1.f/256.f);
                    sAB += A*B; sAA += A*A; sBB += B*B;
                }
            }
            float dab = sqrtf(fmaxf(sAB*(1.f/256.f), 0.f) + 1e-8f);
            float daa = sqrtf(fmaxf(sAA*(1.f/256.f), 0.f) + 1e-8f);
            float dbb = sqrtf(fmaxf(sBB*(1.f/256.f), 0.f) + 1e-8f);
            cor += dab / sqrtf(daa*dbb + 1e-8f);
        }
    }
    *cor_out = cor;
}

// ---------------- degree count ----------------
__global__ void count_kernel(const int* __restrict__ head, float* __restrict__ cnt) {
    int e = blockIdx.x * blockDim.x + threadIdx.x;
    if (e < N_EDGES) atomicAdd(&cnt[head[e]], 1.0f);
}

// ---------------- dis = softmax(att, -1) @ weight (4x64) ----------------
__global__ void dis_kernel(const float* __restrict__ att, const float* __restrict__ weight,
                           float* __restrict__ dis) {
    int tid = threadIdx.x;           // 256 threads: (f,d)
    int f = tid >> 6, d = tid & 63;
    float m = -1e30f;
    for (int r = 0; r < N_REL; ++r) m = fmaxf(m, att[f*N_REL + r]);
    float w[N_REL]; float s = 0.f;
    for (int r = 0; r < N_REL; ++r) { w[r] = expf(att[f*N_REL + r] - m); s += w[r]; }
    float acc = 0.f;
    for (int r = 0; r < N_REL; ++r) acc += (w[r] / s) * weight[r*DD + d];
    dis[f*DD + d] = acc;
}

// ---------------- edge message scatter: agg[head] += ent[tail]*weight[type-1] ----------------
__global__ __launch_bounds__(256) void edge_scatter_kernel(const int* __restrict__ eidx,
                                                           const int* __restrict__ etype,
                                                           const float* __restrict__ ent,
                                                           const float* __restrict__ weight,
                                                           float* __restrict__ agg) {
    int idx = blockIdx.x * 256 + threadIdx.x;   // < N_EDGES*64 = 128M
    int e = idx >> 6;
    int d = idx & 63;
    int h = eidx[e];
    int t = eidx[N_EDGES + e];
    int r = etype[e] - 1;
    float v = ent[(size_t)t * DD + d] * weight[r * DD + d];
    atomicAdd(&agg[(size_t)h * DD + d], v);
}

// ---------------- interact scatter: uagg[row] += val * ent[col] ----------------
__global__ __launch_bounds__(256) void user_scatter_kernel(const int* __restrict__ irow,
                                                           const int* __restrict__ icol,
                                                           const float* __restrict__ ival,
                                                           const float* __restrict__ ent,
                                                           float* __restrict__ uagg) {
    int idx = blockIdx.x * 256 + threadIdx.x;   // < NNZ*64
    int n = idx >> 6;
    int d = idx & 63;
    int row = irow[n];
    int col = icol[n];
    float v = ival[n] * ent[(size_t)col * DD + d];
    atomicAdd(&uagg[(size_t)row * DD + d], v);
}

// ---------------- score = softmax(user @ latent^T, axis=1), wave per user ----------------
__global__ __launch_bounds__(256) void score_kernel(const float* __restrict__ user,
                                                    const float* __restrict__ latent,
                                                    float* __restrict__ score) {
    int u = blockIdx.x * 4 + (threadIdx.x >> 6);
    int lane = threadIdx.x & 63;
    if (u >= N_USERS) return;
    float v = user[(size_t)u * DD + lane];
    float p0 = v * latent[0*DD + lane];
    float p1 = v * latent[1*DD + lane];
    float p2 = v * latent[2*DD + lane];
    float p3 = v * latent[3*DD + lane];
    for (int off = 32; off; off >>= 1) {
        p0 += __shfl_down(p0, off, 64);
        p1 += __shfl_down(p1, off, 64);
        p2 += __shfl_down(p2, off, 64);
        p3 += __shfl_down(p3, off, 64);
    }
    if (lane == 0) {
        float m = fmaxf(fmaxf(p0, p1), fmaxf(p2, p3));
        float e0 = expf(p0 - m), e1 = expf(p1 - m), e2 = expf(p2 - m), e3 = expf(p3 - m);
        float s = e0 + e1 + e2 + e3;
        score[u*4+0] = e0/s; score[u*4+1] = e1/s; score[u*4+2] = e2/s; score[u*4+3] = e3/s;
    }
}

// ---------------- entity update: normalize(agg/denom), cur=, res+= ----------------
__global__ __launch_bounds__(256) void entity_update_kernel(const float* __restrict__ agg,
                                                            const float* __restrict__ cnt,
                                                            float* __restrict__ cur,
                                                            float* __restrict__ res) {
    int i = blockIdx.x * 4 + (threadIdx.x >> 6);
    int lane = threadIdx.x & 63;
    float v = agg[(size_t)i * DD + lane] / fmaxf(cnt[i], 1.0f);
    float ss = v * v;
    for (int off = 32; off; off >>= 1) ss += __shfl_xor(ss, off, 64);
    float nrm = sqrtf(ss);
    v = v / fmaxf(nrm, 1e-12f);
    cur[(size_t)i * DD + lane] = v;
    res[(size_t)i * DD + lane] += v;
}

// ---------------- user update: normalize(uagg*(1+mix)), cur=, res+= ----------------
__global__ __launch_bounds__(256) void user_update_kernel(const float* __restrict__ agg,
                                                          const float* __restrict__ score,
                                                          const float* __restrict__ dis,
                                                          float* __restrict__ cur,
                                                          float* __restrict__ res) {
    int u = blockIdx.x * 4 + (threadIdx.x >> 6);
    int lane = threadIdx.x & 63;
    float s0 = score[u*4+0], s1 = score[u*4+1], s2 = score[u*4+2], s3 = score[u*4+3];
    float mix = dis[0*DD+lane]*s0 + dis[1*DD+lane]*s1 + dis[2*DD+lane]*s2 + dis[3*DD+lane]*s3;
    float ua = agg[(size_t)u * DD + lane];
    float v = ua * mix + ua;
    float ss = v * v;
    for (int off = 32; off; off >>= 1) ss += __shfl_xor(ss, off, 64);
    v = v / fmaxf(sqrtf(ss), 1e-12f);
    cur[(size_t)u * DD + lane] = v;
    res[(size_t)u * DD + lane] += v;
}

extern "C" void kernel_launch(void* const* d_in, const int* in_sizes, int n_in,
                              void* d_out, int out_size, void* d_ws, size_t ws_size,
                              hipStream_t stream) {
    const float* user_emb   = (const float*)d_in[0];
    const float* entity_emb = (const float*)d_in[1];
    const float* latent     = (const float*)d_in[2];
    const float* weight     = (const float*)d_in[3];
    const float* att        = (const float*)d_in[4];
    const float* ival       = (const float*)d_in[5];
    const int*   eidx       = (const int*)d_in[6];
    const int*   etype      = (const int*)d_in[7];
    const int*   irow       = (const int*)d_in[8];
    const int*   icol       = (const int*)d_in[9];

    float* out        = (float*)d_out;
    float* entity_res = out;                                   // N_ITEMS*64
    float* user_res   = out + (size_t)N_ITEMS * DD;            // N_USERS*64
    float* cor_out    = out + (size_t)N_ITEMS * DD + (size_t)N_USERS * DD;

    char* ws = (char*)d_ws;
    float* cur_ent = (float*)ws;  ws += (size_t)N_ITEMS * DD * 4;
    float* cur_usr = (float*)ws;  ws += (size_t)N_USERS * DD * 4;
    float* ent_agg = (float*)ws;  ws += (size_t)N_ITEMS * DD * 4;
    float* usr_agg = (float*)ws;  ws += (size_t)N_USERS * DD * 4;
    float* cnt     = (float*)ws;  ws += (size_t)N_ITEMS * 4;
    float* score   = (float*)ws;  ws += (size_t)N_USERS * 4 * 4;
    float* dis     = (float*)ws;  ws += 256 * 4;

    // init
    hipMemcpyAsync(cur_ent,    entity_emb, (size_t)N_ITEMS * DD * 4, hipMemcpyDeviceToDevice, stream);
    hipMemcpyAsync(cur_usr,    user_emb,   (size_t)N_USERS * DD * 4, hipMemcpyDeviceToDevice, stream);
    hipMemcpyAsync(entity_res, entity_emb, (size_t)N_ITEMS * DD * 4, hipMemcpyDeviceToDevice, stream);
    hipMemcpyAsync(user_res,   user_emb,   (size_t)N_USERS * DD * 4, hipMemcpyDeviceToDevice, stream);
    hipMemsetAsync(cnt, 0, (size_t)N_ITEMS * 4, stream);

    cor_kernel<<<1, 64, 0, stream>>>(att, cor_out);
    count_kernel<<<(N_EDGES + 255) / 256, 256, 0, stream>>>(eidx, cnt);
    dis_kernel<<<1, 256, 0, stream>>>(att, weight, dis);

    for (int layer = 0; layer < 2; ++layer) {
        hipMemsetAsync(ent_agg, 0, (size_t)N_ITEMS * DD * 4, stream);
        hipMemsetAsync(usr_agg, 0, (size_t)N_USERS * DD * 4, stream);

        edge_scatter_kernel<<<(N_EDGES * 64) / 256, 256, 0, stream>>>(eidx, etype, cur_ent, weight, ent_agg);
        user_scatter_kernel<<<(NNZ * 64) / 256, 256, 0, stream>>>(irow, icol, ival, cur_ent, usr_agg);
        score_kernel<<<N_USERS / 4, 256, 0, stream>>>(cur_usr, latent, score);

        entity_update_kernel<<<N_ITEMS / 4, 256, 0, stream>>>(ent_agg, cnt, cur_ent, entity_res);
        user_update_kernel<<<N_USERS / 4, 256, 0, stream>>>(usr_agg, score, dis, cur_usr, user_res);
    }
}

// Round 2
// 2067.716 us; speedup vs baseline: 1.1855x; 1.1855x over previous
//
#include <hip/hip_runtime.h>

#define N_USERS 100000
#define N_ITEMS 150000
#define N_REL 16
#define N_FACT 4
#define DD 64
#define N_EDGES 2000000
#define NNZ 2000000

// ---------------- cor: parallel over 256 (a,b) cells, 6 pairs looped ----------------
__global__ __launch_bounds__(256) void cor_kernel(const float* __restrict__ att,
                                                  float* __restrict__ cor_out) {
    __shared__ float sA[256], sB[256];
    __shared__ float srx[16], scx[16], sry[16], scy[16];
    __shared__ float stotx, stoty;
    int t = threadIdx.x;
    int a = t >> 4, b = t & 15;
    float cor_acc = 0.f;   // only thread 0's value is used
    for (int i = 0; i < N_FACT; ++i) {
        for (int j = i + 1; j < N_FACT; ++j) {
            const float* t1 = att + i * N_REL;
            const float* t2 = att + j * N_REL;
            float d1 = t1[a] - t1[b];
            float d2 = t2[a] - t2[b];
            float dx = sqrtf(d1 * d1 + 1e-8f);   // (t1a-t1b)^2 >= 0, matches max(...,0)
            float dy = sqrtf(d2 * d2 + 1e-8f);
            sA[t] = dx; sB[t] = dy;
            __syncthreads();
            if (t < 16)      { float s = 0; for (int k = 0; k < 16; ++k) s += sA[t * 16 + k]; srx[t] = s; }
            else if (t < 32) { int c = t & 15; float s = 0; for (int k = 0; k < 16; ++k) s += sA[k * 16 + c]; scx[c] = s; }
            else if (t < 48) { int r = t & 15; float s = 0; for (int k = 0; k < 16; ++k) s += sB[r * 16 + k]; sry[r] = s; }
            else if (t < 64) { int c = t & 15; float s = 0; for (int k = 0; k < 16; ++k) s += sB[k * 16 + c]; scy[c] = s; }
            __syncthreads();
            if (t == 0)  { float s = 0; for (int k = 0; k < 16; ++k) s += srx[k]; stotx = s; }
            if (t == 64) { float s = 0; for (int k = 0; k < 16; ++k) s += sry[k]; stoty = s; }
            __syncthreads();
            float A = dx - scx[b] * 0.0625f - srx[a] * 0.0625f + stotx * (1.f / 256.f);
            float B = dy - scy[b] * 0.0625f - sry[a] * 0.0625f + stoty * (1.f / 256.f);
            float vab = A * B, vaa = A * A, vbb = B * B;
            for (int off = 32; off; off >>= 1) {
                vab += __shfl_xor(vab, off, 64);
                vaa += __shfl_xor(vaa, off, 64);
                vbb += __shfl_xor(vbb, off, 64);
            }
            __syncthreads();   // done reading sA/sB for this pair
            if ((t & 63) == 0) {
                int w = t >> 6;
                sA[w] = vab; sA[4 + w] = vaa; sA[8 + w] = vbb;
            }
            __syncthreads();
            if (t == 0) {
                float sAB = sA[0] + sA[1] + sA[2] + sA[3];
                float sAA = sA[4] + sA[5] + sA[6] + sA[7];
                float sBB = sA[8] + sA[9] + sA[10] + sA[11];
                float dab = sqrtf(fmaxf(sAB * (1.f / 256.f), 0.f) + 1e-8f);
                float daa = sqrtf(fmaxf(sAA * (1.f / 256.f), 0.f) + 1e-8f);
                float dbb = sqrtf(fmaxf(sBB * (1.f / 256.f), 0.f) + 1e-8f);
                cor_acc += dab / sqrtf(daa * dbb + 1e-8f);
            }
            __syncthreads();
        }
    }
    if (t == 0) *cor_out = cor_acc;
}

// ---------------- degree count ----------------
__global__ void count_kernel(const int* __restrict__ head, float* __restrict__ cnt) {
    int e = blockIdx.x * blockDim.x + threadIdx.x;
    if (e < N_EDGES) atomicAdd(&cnt[head[e]], 1.0f);
}

// ---------------- dis = softmax(att, -1) @ weight (4x64) ----------------
__global__ void dis_kernel(const float* __restrict__ att, const float* __restrict__ weight,
                           float* __restrict__ dis) {
    int tid = threadIdx.x;           // 256 threads: (f,d)
    int f = tid >> 6, d = tid & 63;
    float m = -1e30f;
    for (int r = 0; r < N_REL; ++r) m = fmaxf(m, att[f * N_REL + r]);
    float w[N_REL]; float s = 0.f;
    for (int r = 0; r < N_REL; ++r) { w[r] = expf(att[f * N_REL + r] - m); s += w[r]; }
    float acc = 0.f;
    for (int r = 0; r < N_REL; ++r) acc += (w[r] / s) * weight[r * DD + d];
    dis[f * DD + d] = acc;
}

// ---------------- edge message scatter: agg[head] += ent[tail]*weight[type-1] ----------------
__global__ __launch_bounds__(256) void edge_scatter_kernel(const int* __restrict__ eidx,
                                                           const int* __restrict__ etype,
                                                           const float* __restrict__ ent,
                                                           const float* __restrict__ weight,
                                                           float* __restrict__ agg) {
    int idx = blockIdx.x * 256 + threadIdx.x;   // < N_EDGES*64 = 128M
    int e = idx >> 6;
    int d = idx & 63;
    int h = eidx[e];
    int t = eidx[N_EDGES + e];
    int r = etype[e] - 1;
    float v = ent[(size_t)t * DD + d] * weight[r * DD + d];
    atomicAdd(&agg[(size_t)h * DD + d], v);
}

// ---------------- interact scatter: uagg[row] += val * ent[col] ----------------
__global__ __launch_bounds__(256) void user_scatter_kernel(const int* __restrict__ irow,
                                                           const int* __restrict__ icol,
                                                           const float* __restrict__ ival,
                                                           const float* __restrict__ ent,
                                                           float* __restrict__ uagg) {
    int idx = blockIdx.x * 256 + threadIdx.x;   // < NNZ*64
    int n = idx >> 6;
    int d = idx & 63;
    int row = irow[n];
    int col = icol[n];
    float v = ival[n] * ent[(size_t)col * DD + d];
    atomicAdd(&uagg[(size_t)row * DD + d], v);
}

// ---------------- score = softmax(user @ latent^T, axis=1), wave per user ----------------
__global__ __launch_bounds__(256) void score_kernel(const float* __restrict__ user,
                                                    const float* __restrict__ latent,
                                                    float* __restrict__ score) {
    int u = blockIdx.x * 4 + (threadIdx.x >> 6);
    int lane = threadIdx.x & 63;
    if (u >= N_USERS) return;
    float v = user[(size_t)u * DD + lane];
    float p0 = v * latent[0 * DD + lane];
    float p1 = v * latent[1 * DD + lane];
    float p2 = v * latent[2 * DD + lane];
    float p3 = v * latent[3 * DD + lane];
    for (int off = 32; off; off >>= 1) {
        p0 += __shfl_down(p0, off, 64);
        p1 += __shfl_down(p1, off, 64);
        p2 += __shfl_down(p2, off, 64);
        p3 += __shfl_down(p3, off, 64);
    }
    if (lane == 0) {
        float m = fmaxf(fmaxf(p0, p1), fmaxf(p2, p3));
        float e0 = expf(p0 - m), e1 = expf(p1 - m), e2 = expf(p2 - m), e3 = expf(p3 - m);
        float s = e0 + e1 + e2 + e3;
        score[u * 4 + 0] = e0 / s; score[u * 4 + 1] = e1 / s;
        score[u * 4 + 2] = e2 / s; score[u * 4 + 3] = e3 / s;
    }
}

// ---------------- entity update: normalize(agg/denom), cur=, res+= ----------------
__global__ __launch_bounds__(256) void entity_update_kernel(const float* __restrict__ agg,
                                                            const float* __restrict__ cnt,
                                                            float* __restrict__ cur,
                                                            float* __restrict__ res) {
    int i = blockIdx.x * 4 + (threadIdx.x >> 6);
    int lane = threadIdx.x & 63;
    float v = agg[(size_t)i * DD + lane] / fmaxf(cnt[i], 1.0f);
    float ss = v * v;
    for (int off = 32; off; off >>= 1) ss += __shfl_xor(ss, off, 64);
    float nrm = sqrtf(ss);
    v = v / fmaxf(nrm, 1e-12f);
    cur[(size_t)i * DD + lane] = v;
    res[(size_t)i * DD + lane] += v;
}

// ---------------- user update: normalize(uagg*(1+mix)), cur=, res+= ----------------
__global__ __launch_bounds__(256) void user_update_kernel(const float* __restrict__ agg,
                                                          const float* __restrict__ score,
                                                          const float* __restrict__ dis,
                                                          float* __restrict__ cur,
                                                          float* __restrict__ res) {
    int u = blockIdx.x * 4 + (threadIdx.x >> 6);
    int lane = threadIdx.x & 63;
    float s0 = score[u * 4 + 0], s1 = score[u * 4 + 1], s2 = score[u * 4 + 2], s3 = score[u * 4 + 3];
    float mix = dis[0 * DD + lane] * s0 + dis[1 * DD + lane] * s1
              + dis[2 * DD + lane] * s2 + dis[3 * DD + lane] * s3;
    float ua = agg[(size_t)u * DD + lane];
    float v = ua * mix + ua;
    float ss = v * v;
    for (int off = 32; off; off >>= 1) ss += __shfl_xor(ss, off, 64);
    v = v / fmaxf(sqrtf(ss), 1e-12f);
    cur[(size_t)u * DD + lane] = v;
    res[(size_t)u * DD + lane] += v;
}

extern "C" void kernel_launch(void* const* d_in, const int* in_sizes, int n_in,
                              void* d_out, int out_size, void* d_ws, size_t ws_size,
                              hipStream_t stream) {
    const float* user_emb   = (const float*)d_in[0];
    const float* entity_emb = (const float*)d_in[1];
    const float* latent     = (const float*)d_in[2];
    const float* weight     = (const float*)d_in[3];
    const float* att        = (const float*)d_in[4];
    const float* ival       = (const float*)d_in[5];
    const int*   eidx       = (const int*)d_in[6];
    const int*   etype      = (const int*)d_in[7];
    const int*   irow       = (const int*)d_in[8];
    const int*   icol       = (const int*)d_in[9];

    float* out        = (float*)d_out;
    float* entity_res = out;                                   // N_ITEMS*64
    float* user_res   = out + (size_t)N_ITEMS * DD;            // N_USERS*64
    float* cor_out    = out + (size_t)N_ITEMS * DD + (size_t)N_USERS * DD;

    char* ws = (char*)d_ws;
    float* cur_ent = (float*)ws;  ws += (size_t)N_ITEMS * DD * 4;
    float* cur_usr = (float*)ws;  ws += (size_t)N_USERS * DD * 4;
    float* ent_agg = (float*)ws;  ws += (size_t)N_ITEMS * DD * 4;
    float* usr_agg = (float*)ws;  ws += (size_t)N_USERS * DD * 4;
    float* cnt     = (float*)ws;  ws += (size_t)N_ITEMS * 4;
    float* score   = (float*)ws;  ws += (size_t)N_USERS * 4 * 4;
    float* dis     = (float*)ws;  ws += 256 * 4;

    // init
    hipMemcpyAsync(cur_ent,    entity_emb, (size_t)N_ITEMS * DD * 4, hipMemcpyDeviceToDevice, stream);
    hipMemcpyAsync(cur_usr,    user_emb,   (size_t)N_USERS * DD * 4, hipMemcpyDeviceToDevice, stream);
    hipMemcpyAsync(entity_res, entity_emb, (size_t)N_ITEMS * DD * 4, hipMemcpyDeviceToDevice, stream);
    hipMemcpyAsync(user_res,   user_emb,   (size_t)N_USERS * DD * 4, hipMemcpyDeviceToDevice, stream);
    hipMemsetAsync(cnt, 0, (size_t)N_ITEMS * 4, stream);

    cor_kernel<<<1, 256, 0, stream>>>(att, cor_out);
    count_kernel<<<(N_EDGES + 255) / 256, 256, 0, stream>>>(eidx, cnt);
    dis_kernel<<<1, 256, 0, stream>>>(att, weight, dis);

    for (int layer = 0; layer < 2; ++layer) {
        hipMemsetAsync(ent_agg, 0, (size_t)N_ITEMS * DD * 4, stream);
        hipMemsetAsync(usr_agg, 0, (size_t)N_USERS * DD * 4, stream);

        edge_scatter_kernel<<<(N_EDGES * 64) / 256, 256, 0, stream>>>(eidx, etype, cur_ent, weight, ent_agg);
        user_scatter_kernel<<<(NNZ * 64) / 256, 256, 0, stream>>>(irow, icol, ival, cur_ent, usr_agg);
        score_kernel<<<N_USERS / 4, 256, 0, stream>>>(cur_usr, latent, score);

        entity_update_kernel<<<N_ITEMS / 4, 256, 0, stream>>>(ent_agg, cnt, cur_ent, entity_res);
        user_update_kernel<<<N_USERS / 4, 256, 0, stream>>>(usr_agg, score, dis, cur_usr, user_res);
    }
}

// Round 3
// 1025.208 us; speedup vs baseline: 2.3909x; 2.0169x over previous
//
#include <hip/hip_runtime.h>

#define N_USERS 100000
#define N_ITEMS 150000
#define N_REL 16
#define N_FACT 4
#define DD 64
#define N_EDGES 2000000
#define NNZ 2000000

// ---------------- cor: parallel over 256 (a,b) cells, 6 pairs looped ----------------
__global__ __launch_bounds__(256) void cor_kernel(const float* __restrict__ att,
                                                  float* __restrict__ cor_out) {
    __shared__ float sA[256], sB[256];
    __shared__ float srx[16], scx[16], sry[16], scy[16];
    __shared__ float stotx, stoty;
    int t = threadIdx.x;
    int a = t >> 4, b = t & 15;
    float cor_acc = 0.f;
    for (int i = 0; i < N_FACT; ++i) {
        for (int j = i + 1; j < N_FACT; ++j) {
            const float* t1 = att + i * N_REL;
            const float* t2 = att + j * N_REL;
            float d1 = t1[a] - t1[b];
            float d2 = t2[a] - t2[b];
            float dx = sqrtf(d1 * d1 + 1e-8f);
            float dy = sqrtf(d2 * d2 + 1e-8f);
            sA[t] = dx; sB[t] = dy;
            __syncthreads();
            if (t < 16)      { float s = 0; for (int k = 0; k < 16; ++k) s += sA[t * 16 + k]; srx[t] = s; }
            else if (t < 32) { int c = t & 15; float s = 0; for (int k = 0; k < 16; ++k) s += sA[k * 16 + c]; scx[c] = s; }
            else if (t < 48) { int r = t & 15; float s = 0; for (int k = 0; k < 16; ++k) s += sB[r * 16 + k]; sry[r] = s; }
            else if (t < 64) { int c = t & 15; float s = 0; for (int k = 0; k < 16; ++k) s += sB[k * 16 + c]; scy[c] = s; }
            __syncthreads();
            if (t == 0)  { float s = 0; for (int k = 0; k < 16; ++k) s += srx[k]; stotx = s; }
            if (t == 64) { float s = 0; for (int k = 0; k < 16; ++k) s += sry[k]; stoty = s; }
            __syncthreads();
            float A = dx - scx[b] * 0.0625f - srx[a] * 0.0625f + stotx * (1.f / 256.f);
            float B = dy - scy[b] * 0.0625f - sry[a] * 0.0625f + stoty * (1.f / 256.f);
            float vab = A * B, vaa = A * A, vbb = B * B;
            for (int off = 32; off; off >>= 1) {
                vab += __shfl_xor(vab, off, 64);
                vaa += __shfl_xor(vaa, off, 64);
                vbb += __shfl_xor(vbb, off, 64);
            }
            __syncthreads();
            if ((t & 63) == 0) {
                int w = t >> 6;
                sA[w] = vab; sA[4 + w] = vaa; sA[8 + w] = vbb;
            }
            __syncthreads();
            if (t == 0) {
                float sAB = sA[0] + sA[1] + sA[2] + sA[3];
                float sAA = sA[4] + sA[5] + sA[6] + sA[7];
                float sBB = sA[8] + sA[9] + sA[10] + sA[11];
                float dab = sqrtf(fmaxf(sAB * (1.f / 256.f), 0.f) + 1e-8f);
                float daa = sqrtf(fmaxf(sAA * (1.f / 256.f), 0.f) + 1e-8f);
                float dbb = sqrtf(fmaxf(sBB * (1.f / 256.f), 0.f) + 1e-8f);
                cor_acc += dab / sqrtf(daa * dbb + 1e-8f);
            }
            __syncthreads();
        }
    }
    if (t == 0) *cor_out = cor_acc;
}

// ---------------- dis = softmax(att, -1) @ weight (4x64) ----------------
__global__ void dis_kernel(const float* __restrict__ att, const float* __restrict__ weight,
                           float* __restrict__ dis) {
    int tid = threadIdx.x;
    int f = tid >> 6, d = tid & 63;
    float m = -1e30f;
    for (int r = 0; r < N_REL; ++r) m = fmaxf(m, att[f * N_REL + r]);
    float w[N_REL]; float s = 0.f;
    for (int r = 0; r < N_REL; ++r) { w[r] = expf(att[f * N_REL + r] - m); s += w[r]; }
    float acc = 0.f;
    for (int r = 0; r < N_REL; ++r) acc += (w[r] / s) * weight[r * DD + d];
    dis[f * DD + d] = acc;
}

// ---------------- CSR build: count ----------------
__global__ void count_int_kernel(const int* __restrict__ idx, int* __restrict__ cnt, int n) {
    int e = blockIdx.x * blockDim.x + threadIdx.x;
    if (e < n) atomicAdd(&cnt[idx[e]], 1);
}

// ---------------- CSR build: 3-kernel exclusive scan ----------------
// A: per-block (1024 elems) sum
__global__ __launch_bounds__(256) void scanA_kernel(const int* __restrict__ cnt,
                                                    int* __restrict__ bsum, int n) {
    __shared__ int lds[256];
    int t = threadIdx.x;
    int base = blockIdx.x * 1024 + t * 4;
    int s = 0;
    #pragma unroll
    for (int k = 0; k < 4; ++k) { int i = base + k; if (i < n) s += cnt[i]; }
    lds[t] = s; __syncthreads();
    for (int off = 128; off; off >>= 1) { if (t < off) lds[t] += lds[t + off]; __syncthreads(); }
    if (t == 0) bsum[blockIdx.x] = lds[0];
}
// B: single-block exclusive scan of block sums (G <= 256); also writes off[n] = total
__global__ __launch_bounds__(256) void scanB_kernel(int* __restrict__ bsum, int G,
                                                    int* __restrict__ off, int n) {
    __shared__ int lds[256];
    int t = threadIdx.x;
    int v = (t < G) ? bsum[t] : 0;
    lds[t] = v; __syncthreads();
    for (int o = 1; o < 256; o <<= 1) {
        int add = (t >= o) ? lds[t - o] : 0;
        __syncthreads();
        lds[t] += add;
        __syncthreads();
    }
    if (t < G) bsum[t] = lds[t] - v;          // exclusive
    if (t == G - 1) off[n] = lds[t];          // total
}
// C: per-block re-scan, write off + cursor (cursor aliases cnt; read-before-write per thread)
__global__ __launch_bounds__(256) void scanC_kernel(int* __restrict__ cnt_cursor,
                                                    const int* __restrict__ bsum,
                                                    int* __restrict__ off, int n) {
    __shared__ int lds[256];
    int t = threadIdx.x, blk = blockIdx.x;
    int base = blk * 1024 + t * 4;
    int c[4];
    #pragma unroll
    for (int k = 0; k < 4; ++k) { int i = base + k; c[k] = (i < n) ? cnt_cursor[i] : 0; }
    int s = c[0] + c[1] + c[2] + c[3];
    lds[t] = s; __syncthreads();
    for (int o = 1; o < 256; o <<= 1) {
        int add = (t >= o) ? lds[t - o] : 0;
        __syncthreads();
        lds[t] += add;
        __syncthreads();
    }
    int texcl = lds[t] - s;
    int run = bsum[blk] + texcl;
    #pragma unroll
    for (int k = 0; k < 4; ++k) {
        int i = base + k;
        if (i < n) { off[i] = run; cnt_cursor[i] = run; run += c[k]; }
    }
}

// ---------------- CSR build: placement ----------------
__global__ void place_e_kernel(const int* __restrict__ eidx, const int* __restrict__ etype,
                               int* __restrict__ cursor, int* __restrict__ pack) {
    int e = blockIdx.x * blockDim.x + threadIdx.x;
    if (e >= N_EDGES) return;
    int h = eidx[e];
    int t = eidx[N_EDGES + e];
    int r = etype[e] - 1;
    int pos = atomicAdd(&cursor[h], 1);
    pack[pos] = t | (r << 18);                // t < 2^18, r < 16
}
__global__ void place_u_kernel(const int* __restrict__ irow, const int* __restrict__ icol,
                               const float* __restrict__ ival,
                               int* __restrict__ cursor,
                               int* __restrict__ ucol, float* __restrict__ uval) {
    int n = blockIdx.x * blockDim.x + threadIdx.x;
    if (n >= NNZ) return;
    int pos = atomicAdd(&cursor[irow[n]], 1);
    ucol[pos] = icol[n];
    uval[pos] = ival[n];
}

// ---------------- entity layer: gather + mean + normalize + residual ----------------
__global__ __launch_bounds__(256) void entity_layer_kernel(const int* __restrict__ off,
                                                           const int* __restrict__ pack,
                                                           const float* __restrict__ entIn,
                                                           const float* __restrict__ weight,
                                                           float* __restrict__ entOut,
                                                           float* __restrict__ res) {
    int i = blockIdx.x * 4 + (threadIdx.x >> 6);
    int lane = threadIdx.x & 63;
    int beg = off[i], end = off[i + 1];
    int deg = end - beg;
    float acc = 0.f;
    for (int base = 0; base < deg; base += 64) {
        int m = min(64, deg - base);
        int pk = 0;
        if (lane < m) pk = pack[beg + base + lane];
        for (int k = 0; k < m; ++k) {
            int p = __shfl(pk, k, 64);
            int tt = p & 0x3FFFF;
            int r  = p >> 18;
            acc += entIn[(size_t)tt * DD + lane] * weight[r * DD + lane];
        }
    }
    float v = acc / fmaxf((float)deg, 1.f);
    float ss = v * v;
    for (int o = 32; o; o >>= 1) ss += __shfl_xor(ss, o, 64);
    v /= fmaxf(sqrtf(ss), 1e-12f);
    entOut[(size_t)i * DD + lane] = v;
    res[(size_t)i * DD + lane] += v;
}

// ---------------- user layer: score + gather + mix + normalize + residual ----------------
__global__ __launch_bounds__(256) void user_layer_kernel(const int* __restrict__ off,
                                                         const int* __restrict__ ucol,
                                                         const float* __restrict__ uval,
                                                         const float* __restrict__ entIn,
                                                         const float* __restrict__ latent,
                                                         const float* __restrict__ dis,
                                                         float* __restrict__ usr,
                                                         float* __restrict__ res) {
    int u = blockIdx.x * 4 + (threadIdx.x >> 6);
    int lane = threadIdx.x & 63;
    float uv = usr[(size_t)u * DD + lane];
    float p0 = uv * latent[0 * DD + lane];
    float p1 = uv * latent[1 * DD + lane];
    float p2 = uv * latent[2 * DD + lane];
    float p3 = uv * latent[3 * DD + lane];
    for (int o = 32; o; o >>= 1) {
        p0 += __shfl_xor(p0, o, 64);
        p1 += __shfl_xor(p1, o, 64);
        p2 += __shfl_xor(p2, o, 64);
        p3 += __shfl_xor(p3, o, 64);
    }
    float m = fmaxf(fmaxf(p0, p1), fmaxf(p2, p3));
    float e0 = expf(p0 - m), e1 = expf(p1 - m), e2 = expf(p2 - m), e3 = expf(p3 - m);
    float sinv = 1.f / (e0 + e1 + e2 + e3);
    float s0 = e0 * sinv, s1 = e1 * sinv, s2 = e2 * sinv, s3 = e3 * sinv;
    float mix = dis[0 * DD + lane] * s0 + dis[1 * DD + lane] * s1
              + dis[2 * DD + lane] * s2 + dis[3 * DD + lane] * s3;

    int beg = off[u], end = off[u + 1];
    int deg = end - beg;
    float acc = 0.f;
    for (int base = 0; base < deg; base += 64) {
        int mm = min(64, deg - base);
        int c = 0; float vv = 0.f;
        if (lane < mm) { c = ucol[beg + base + lane]; vv = uval[beg + base + lane]; }
        for (int k = 0; k < mm; ++k) {
            int cc = __shfl(c, k, 64);
            float val = __shfl(vv, k, 64);
            acc += val * entIn[(size_t)cc * DD + lane];
        }
    }
    float v = acc * mix + acc;
    float ss = v * v;
    for (int o = 32; o; o >>= 1) ss += __shfl_xor(ss, o, 64);
    v /= fmaxf(sqrtf(ss), 1e-12f);
    usr[(size_t)u * DD + lane] = v;
    res[(size_t)u * DD + lane] += v;
}

extern "C" void kernel_launch(void* const* d_in, const int* in_sizes, int n_in,
                              void* d_out, int out_size, void* d_ws, size_t ws_size,
                              hipStream_t stream) {
    const float* user_emb   = (const float*)d_in[0];
    const float* entity_emb = (const float*)d_in[1];
    const float* latent     = (const float*)d_in[2];
    const float* weight     = (const float*)d_in[3];
    const float* att        = (const float*)d_in[4];
    const float* ival       = (const float*)d_in[5];
    const int*   eidx       = (const int*)d_in[6];
    const int*   etype      = (const int*)d_in[7];
    const int*   irow       = (const int*)d_in[8];
    const int*   icol       = (const int*)d_in[9];

    float* out        = (float*)d_out;
    float* entity_res = out;
    float* user_res   = out + (size_t)N_ITEMS * DD;
    float* cor_out    = out + (size_t)N_ITEMS * DD + (size_t)N_USERS * DD;

    char* ws = (char*)d_ws;
    float* ent0   = (float*)ws;  ws += (size_t)N_ITEMS * DD * 4;
    float* ent1   = (float*)ws;  ws += (size_t)N_ITEMS * DD * 4;
    float* cur_usr= (float*)ws;  ws += (size_t)N_USERS * DD * 4;
    int*   eoff   = (int*)ws;    ws += (size_t)(N_ITEMS + 1) * 4;
    int*   ecur   = (int*)ws;    ws += (size_t)N_ITEMS * 4;       // doubles as count
    int*   epack  = (int*)ws;    ws += (size_t)N_EDGES * 4;
    int*   uoff   = (int*)ws;    ws += (size_t)(N_USERS + 1) * 4;
    int*   ucur   = (int*)ws;    ws += (size_t)N_USERS * 4;       // doubles as count
    int*   ucol   = (int*)ws;    ws += (size_t)NNZ * 4;
    float* uval   = (float*)ws;  ws += (size_t)NNZ * 4;
    int*   ebsum  = (int*)ws;    ws += 256 * 4;
    int*   ubsum  = (int*)ws;    ws += 256 * 4;
    float* dis    = (float*)ws;  ws += 256 * 4;

    const int GE = (N_ITEMS + 1023) / 1024;   // 147
    const int GU = (N_USERS + 1023) / 1024;   // 98

    // ---- init ----
    hipMemcpyAsync(ent0,       entity_emb, (size_t)N_ITEMS * DD * 4, hipMemcpyDeviceToDevice, stream);
    hipMemcpyAsync(cur_usr,    user_emb,   (size_t)N_USERS * DD * 4, hipMemcpyDeviceToDevice, stream);
    hipMemcpyAsync(entity_res, entity_emb, (size_t)N_ITEMS * DD * 4, hipMemcpyDeviceToDevice, stream);
    hipMemcpyAsync(user_res,   user_emb,   (size_t)N_USERS * DD * 4, hipMemcpyDeviceToDevice, stream);
    hipMemsetAsync(ecur, 0, (size_t)N_ITEMS * 4, stream);
    hipMemsetAsync(ucur, 0, (size_t)N_USERS * 4, stream);

    cor_kernel<<<1, 256, 0, stream>>>(att, cor_out);
    dis_kernel<<<1, 256, 0, stream>>>(att, weight, dis);

    // ---- CSR build (once, reused by both layers) ----
    count_int_kernel<<<(N_EDGES + 255) / 256, 256, 0, stream>>>(eidx, ecur, N_EDGES);
    count_int_kernel<<<(NNZ + 255) / 256, 256, 0, stream>>>(irow, ucur, NNZ);

    scanA_kernel<<<GE, 256, 0, stream>>>(ecur, ebsum, N_ITEMS);
    scanB_kernel<<<1, 256, 0, stream>>>(ebsum, GE, eoff, N_ITEMS);
    scanC_kernel<<<GE, 256, 0, stream>>>(ecur, ebsum, eoff, N_ITEMS);

    scanA_kernel<<<GU, 256, 0, stream>>>(ucur, ubsum, N_USERS);
    scanB_kernel<<<1, 256, 0, stream>>>(ubsum, GU, uoff, N_USERS);
    scanC_kernel<<<GU, 256, 0, stream>>>(ucur, ubsum, uoff, N_USERS);

    place_e_kernel<<<(N_EDGES + 255) / 256, 256, 0, stream>>>(eidx, etype, ecur, epack);
    place_u_kernel<<<(NNZ + 255) / 256, 256, 0, stream>>>(irow, icol, ival, ucur, ucol, uval);

    // ---- layers (double-buffered entity embeddings) ----
    float* entbuf[2] = { ent0, ent1 };
    for (int layer = 0; layer < 2; ++layer) {
        float* eIn  = entbuf[layer & 1];
        float* eOut = entbuf[(layer & 1) ^ 1];
        user_layer_kernel<<<N_USERS / 4, 256, 0, stream>>>(uoff, ucol, uval, eIn, latent, dis,
                                                           cur_usr, user_res);
        entity_layer_kernel<<<N_ITEMS / 4, 256, 0, stream>>>(eoff, epack, eIn, weight,
                                                             eOut, entity_res);
    }
}

// Round 4
// 863.023 us; speedup vs baseline: 2.8403x; 1.1879x over previous
//
#include <hip/hip_runtime.h>

#define N_USERS 100000
#define N_ITEMS 150000
#define N_REL 16
#define N_FACT 4
#define DD 64
#define N_EDGES 2000000
#define NNZ 2000000

// ---------------- cor: parallel over 256 (a,b) cells, 6 pairs looped ----------------
__global__ __launch_bounds__(256) void cor_kernel(const float* __restrict__ att,
                                                  float* __restrict__ cor_out) {
    __shared__ float sA[256], sB[256];
    __shared__ float srx[16], scx[16], sry[16], scy[16];
    __shared__ float stotx, stoty;
    int t = threadIdx.x;
    int a = t >> 4, b = t & 15;
    float cor_acc = 0.f;
    for (int i = 0; i < N_FACT; ++i) {
        for (int j = i + 1; j < N_FACT; ++j) {
            const float* t1 = att + i * N_REL;
            const float* t2 = att + j * N_REL;
            float d1 = t1[a] - t1[b];
            float d2 = t2[a] - t2[b];
            float dx = sqrtf(d1 * d1 + 1e-8f);
            float dy = sqrtf(d2 * d2 + 1e-8f);
            sA[t] = dx; sB[t] = dy;
            __syncthreads();
            if (t < 16)      { float s = 0; for (int k = 0; k < 16; ++k) s += sA[t * 16 + k]; srx[t] = s; }
            else if (t < 32) { int c = t & 15; float s = 0; for (int k = 0; k < 16; ++k) s += sA[k * 16 + c]; scx[c] = s; }
            else if (t < 48) { int r = t & 15; float s = 0; for (int k = 0; k < 16; ++k) s += sB[r * 16 + k]; sry[r] = s; }
            else if (t < 64) { int c = t & 15; float s = 0; for (int k = 0; k < 16; ++k) s += sB[k * 16 + c]; scy[c] = s; }
            __syncthreads();
            if (t == 0)  { float s = 0; for (int k = 0; k < 16; ++k) s += srx[k]; stotx = s; }
            if (t == 64) { float s = 0; for (int k = 0; k < 16; ++k) s += sry[k]; stoty = s; }
            __syncthreads();
            float A = dx - scx[b] * 0.0625f - srx[a] * 0.0625f + stotx * (1.f / 256.f);
            float B = dy - scy[b] * 0.0625f - sry[a] * 0.0625f + stoty * (1.f / 256.f);
            float vab = A * B, vaa = A * A, vbb = B * B;
            for (int off = 32; off; off >>= 1) {
                vab += __shfl_xor(vab, off, 64);
                vaa += __shfl_xor(vaa, off, 64);
                vbb += __shfl_xor(vbb, off, 64);
            }
            __syncthreads();
            if ((t & 63) == 0) {
                int w = t >> 6;
                sA[w] = vab; sA[4 + w] = vaa; sA[8 + w] = vbb;
            }
            __syncthreads();
            if (t == 0) {
                float sAB = sA[0] + sA[1] + sA[2] + sA[3];
                float sAA = sA[4] + sA[5] + sA[6] + sA[7];
                float sBB = sA[8] + sA[9] + sA[10] + sA[11];
                float dab = sqrtf(fmaxf(sAB * (1.f / 256.f), 0.f) + 1e-8f);
                float daa = sqrtf(fmaxf(sAA * (1.f / 256.f), 0.f) + 1e-8f);
                float dbb = sqrtf(fmaxf(sBB * (1.f / 256.f), 0.f) + 1e-8f);
                cor_acc += dab / sqrtf(daa * dbb + 1e-8f);
            }
            __syncthreads();
        }
    }
    if (t == 0) *cor_out = cor_acc;
}

// ---------------- dis = softmax(att, -1) @ weight (4x64) ----------------
__global__ void dis_kernel(const float* __restrict__ att, const float* __restrict__ weight,
                           float* __restrict__ dis) {
    int tid = threadIdx.x;
    int f = tid >> 6, d = tid & 63;
    float m = -1e30f;
    for (int r = 0; r < N_REL; ++r) m = fmaxf(m, att[f * N_REL + r]);
    float w[N_REL]; float s = 0.f;
    for (int r = 0; r < N_REL; ++r) { w[r] = expf(att[f * N_REL + r] - m); s += w[r]; }
    float acc = 0.f;
    for (int r = 0; r < N_REL; ++r) acc += (w[r] / s) * weight[r * DD + d];
    dis[f * DD + d] = acc;
}

// ---------------- CSR build: count (NT loads keep L2 clean) ----------------
__global__ void count_int_kernel(const int* __restrict__ idx, int* __restrict__ cnt, int n) {
    int e = blockIdx.x * blockDim.x + threadIdx.x;
    if (e < n) atomicAdd(&cnt[__builtin_nontemporal_load(&idx[e])], 1);
}

// ---------------- CSR build: 3-kernel exclusive scan ----------------
__global__ __launch_bounds__(256) void scanA_kernel(const int* __restrict__ cnt,
                                                    int* __restrict__ bsum, int n) {
    __shared__ int lds[256];
    int t = threadIdx.x;
    int base = blockIdx.x * 1024 + t * 4;
    int s = 0;
    #pragma unroll
    for (int k = 0; k < 4; ++k) { int i = base + k; if (i < n) s += cnt[i]; }
    lds[t] = s; __syncthreads();
    for (int off = 128; off; off >>= 1) { if (t < off) lds[t] += lds[t + off]; __syncthreads(); }
    if (t == 0) bsum[blockIdx.x] = lds[0];
}
__global__ __launch_bounds__(256) void scanB_kernel(int* __restrict__ bsum, int G,
                                                    int* __restrict__ off, int n) {
    __shared__ int lds[256];
    int t = threadIdx.x;
    int v = (t < G) ? bsum[t] : 0;
    lds[t] = v; __syncthreads();
    for (int o = 1; o < 256; o <<= 1) {
        int add = (t >= o) ? lds[t - o] : 0;
        __syncthreads();
        lds[t] += add;
        __syncthreads();
    }
    if (t < G) bsum[t] = lds[t] - v;
    if (t == G - 1) off[n] = lds[t];
}
__global__ __launch_bounds__(256) void scanC_kernel(int* __restrict__ cnt_cursor,
                                                    const int* __restrict__ bsum,
                                                    int* __restrict__ off, int n) {
    __shared__ int lds[256];
    int t = threadIdx.x, blk = blockIdx.x;
    int base = blk * 1024 + t * 4;
    int c[4];
    #pragma unroll
    for (int k = 0; k < 4; ++k) { int i = base + k; c[k] = (i < n) ? cnt_cursor[i] : 0; }
    int s = c[0] + c[1] + c[2] + c[3];
    lds[t] = s; __syncthreads();
    for (int o = 1; o < 256; o <<= 1) {
        int add = (t >= o) ? lds[t - o] : 0;
        __syncthreads();
        lds[t] += add;
        __syncthreads();
    }
    int texcl = lds[t] - s;
    int run = bsum[blk] + texcl;
    #pragma unroll
    for (int k = 0; k < 4; ++k) {
        int i = base + k;
        if (i < n) { off[i] = run; cnt_cursor[i] = run; run += c[k]; }
    }
}

// ---------------- CSR build: placement (NT reads; cached scattered writes) ----------------
__global__ void place_e_kernel(const int* __restrict__ eidx, const int* __restrict__ etype,
                               int* __restrict__ cursor, int* __restrict__ pack) {
    int e = blockIdx.x * blockDim.x + threadIdx.x;
    if (e >= N_EDGES) return;
    int h = __builtin_nontemporal_load(&eidx[e]);
    int t = __builtin_nontemporal_load(&eidx[N_EDGES + e]);
    int r = __builtin_nontemporal_load(&etype[e]) - 1;
    int pos = atomicAdd(&cursor[h], 1);
    pack[pos] = t | (r << 18);
}
__global__ void place_u_kernel(const int* __restrict__ irow, const int* __restrict__ icol,
                               const float* __restrict__ ival,
                               int* __restrict__ cursor,
                               int* __restrict__ ucol, float* __restrict__ uval) {
    int n = blockIdx.x * blockDim.x + threadIdx.x;
    if (n >= NNZ) return;
    int row = __builtin_nontemporal_load(&irow[n]);
    int col = __builtin_nontemporal_load(&icol[n]);
    float v  = __builtin_nontemporal_load(&ival[n]);
    int pos = atomicAdd(&cursor[row], 1);
    ucol[pos] = col;
    uval[pos] = v;
}

// ---------------- entity layer: 16-lane group x float4, 4 rows/wave ----------------
__global__ __launch_bounds__(256) void entity_layer_kernel(const int* __restrict__ off,
                                                           const int* __restrict__ pack,
                                                           const float4* __restrict__ entIn4,
                                                           const float4* __restrict__ w4,
                                                           float4* __restrict__ entOut4,
                                                           float4* __restrict__ res4) {
    int w = threadIdx.x >> 6;
    int lane = threadIdx.x & 63;
    int g = lane >> 4, li = lane & 15;
    int row = blockIdx.x * 16 + w * 4 + g;
    int beg = off[row];
    int deg = off[row + 1] - beg;
    int mdeg = max(deg, __shfl_xor(deg, 16, 64));
    mdeg = max(mdeg, __shfl_xor(mdeg, 32, 64));
    float4 acc = make_float4(0.f, 0.f, 0.f, 0.f);
    for (int cb = 0; cb < mdeg; cb += 16) {
        int pk = 0;
        if (cb + li < deg) pk = __builtin_nontemporal_load(&pack[beg + cb + li]);
        #pragma unroll
        for (int k = 0; k < 16; ++k) {
            if (cb + k < deg) {
                int p = __shfl(pk, k, 16);
                int tt = p & 0x3FFFF;
                int r  = p >> 18;
                float4 e  = entIn4[(size_t)tt * 16 + li];
                float4 ww = w4[r * 16 + li];
                acc.x += e.x * ww.x; acc.y += e.y * ww.y;
                acc.z += e.z * ww.z; acc.w += e.w * ww.w;
            }
        }
    }
    float inv = 1.f / fmaxf((float)deg, 1.f);
    acc.x *= inv; acc.y *= inv; acc.z *= inv; acc.w *= inv;
    float ss = acc.x * acc.x + acc.y * acc.y + acc.z * acc.z + acc.w * acc.w;
    for (int o = 8; o; o >>= 1) ss += __shfl_xor(ss, o, 16);
    float rn = 1.f / fmaxf(sqrtf(ss), 1e-12f);
    float4 v = make_float4(acc.x * rn, acc.y * rn, acc.z * rn, acc.w * rn);
    entOut4[(size_t)row * 16 + li] = v;
    float4 rr = res4[(size_t)row * 16 + li];
    rr.x += v.x; rr.y += v.y; rr.z += v.z; rr.w += v.w;
    res4[(size_t)row * 16 + li] = rr;
}

// ---------------- user layer: score + 16-lane group gather + mix + norm + residual ----------------
__global__ __launch_bounds__(256) void user_layer_kernel(const int* __restrict__ off,
                                                         const int* __restrict__ ucol,
                                                         const float* __restrict__ uval,
                                                         const float4* __restrict__ entIn4,
                                                         const float4* __restrict__ lat4,
                                                         const float4* __restrict__ dis4,
                                                         float4* __restrict__ usr4,
                                                         float4* __restrict__ res4) {
    int w = threadIdx.x >> 6;
    int lane = threadIdx.x & 63;
    int g = lane >> 4, li = lane & 15;
    int u = blockIdx.x * 16 + w * 4 + g;

    float4 uv = usr4[(size_t)u * 16 + li];
    float4 l0 = lat4[0 * 16 + li], l1 = lat4[1 * 16 + li];
    float4 l2 = lat4[2 * 16 + li], l3 = lat4[3 * 16 + li];
    float p0 = uv.x * l0.x + uv.y * l0.y + uv.z * l0.z + uv.w * l0.w;
    float p1 = uv.x * l1.x + uv.y * l1.y + uv.z * l1.z + uv.w * l1.w;
    float p2 = uv.x * l2.x + uv.y * l2.y + uv.z * l2.z + uv.w * l2.w;
    float p3 = uv.x * l3.x + uv.y * l3.y + uv.z * l3.z + uv.w * l3.w;
    for (int o = 8; o; o >>= 1) {
        p0 += __shfl_xor(p0, o, 16);
        p1 += __shfl_xor(p1, o, 16);
        p2 += __shfl_xor(p2, o, 16);
        p3 += __shfl_xor(p3, o, 16);
    }
    float m = fmaxf(fmaxf(p0, p1), fmaxf(p2, p3));
    float e0 = expf(p0 - m), e1 = expf(p1 - m), e2 = expf(p2 - m), e3 = expf(p3 - m);
    float sinv = 1.f / (e0 + e1 + e2 + e3);
    float s0 = e0 * sinv, s1 = e1 * sinv, s2 = e2 * sinv, s3 = e3 * sinv;
    float4 d0 = dis4[0 * 16 + li], d1 = dis4[1 * 16 + li];
    float4 d2 = dis4[2 * 16 + li], d3 = dis4[3 * 16 + li];
    float4 mix = make_float4(d0.x * s0 + d1.x * s1 + d2.x * s2 + d3.x * s3,
                             d0.y * s0 + d1.y * s1 + d2.y * s2 + d3.y * s3,
                             d0.z * s0 + d1.z * s1 + d2.z * s2 + d3.z * s3,
                             d0.w * s0 + d1.w * s1 + d2.w * s2 + d3.w * s3);

    int beg = off[u];
    int deg = off[u + 1] - beg;
    int mdeg = max(deg, __shfl_xor(deg, 16, 64));
    mdeg = max(mdeg, __shfl_xor(mdeg, 32, 64));
    float4 acc = make_float4(0.f, 0.f, 0.f, 0.f);
    for (int cb = 0; cb < mdeg; cb += 16) {
        int c = 0; float vv = 0.f;
        if (cb + li < deg) {
            c  = __builtin_nontemporal_load(&ucol[beg + cb + li]);
            vv = __builtin_nontemporal_load(&uval[beg + cb + li]);
        }
        #pragma unroll
        for (int k = 0; k < 16; ++k) {
            if (cb + k < deg) {
                int cc = __shfl(c, k, 16);
                float val = __shfl(vv, k, 16);
                float4 e = entIn4[(size_t)cc * 16 + li];
                acc.x += val * e.x; acc.y += val * e.y;
                acc.z += val * e.z; acc.w += val * e.w;
            }
        }
    }
    float4 v = make_float4(acc.x * mix.x + acc.x, acc.y * mix.y + acc.y,
                           acc.z * mix.z + acc.z, acc.w * mix.w + acc.w);
    float ss = v.x * v.x + v.y * v.y + v.z * v.z + v.w * v.w;
    for (int o = 8; o; o >>= 1) ss += __shfl_xor(ss, o, 16);
    float rn = 1.f / fmaxf(sqrtf(ss), 1e-12f);
    v.x *= rn; v.y *= rn; v.z *= rn; v.w *= rn;
    usr4[(size_t)u * 16 + li] = v;
    float4 rr = res4[(size_t)u * 16 + li];
    rr.x += v.x; rr.y += v.y; rr.z += v.z; rr.w += v.w;
    res4[(size_t)u * 16 + li] = rr;
}

extern "C" void kernel_launch(void* const* d_in, const int* in_sizes, int n_in,
                              void* d_out, int out_size, void* d_ws, size_t ws_size,
                              hipStream_t stream) {
    const float* user_emb   = (const float*)d_in[0];
    const float* entity_emb = (const float*)d_in[1];
    const float* latent     = (const float*)d_in[2];
    const float* weight     = (const float*)d_in[3];
    const float* att        = (const float*)d_in[4];
    const float* ival       = (const float*)d_in[5];
    const int*   eidx       = (const int*)d_in[6];
    const int*   etype      = (const int*)d_in[7];
    const int*   irow       = (const int*)d_in[8];
    const int*   icol       = (const int*)d_in[9];

    float* out        = (float*)d_out;
    float* entity_res = out;
    float* user_res   = out + (size_t)N_ITEMS * DD;
    float* cor_out    = out + (size_t)N_ITEMS * DD + (size_t)N_USERS * DD;

    char* ws = (char*)d_ws;
    float* ent0   = (float*)ws;  ws += (size_t)N_ITEMS * DD * 4;
    float* ent1   = (float*)ws;  ws += (size_t)N_ITEMS * DD * 4;
    float* cur_usr= (float*)ws;  ws += (size_t)N_USERS * DD * 4;
    int*   eoff   = (int*)ws;    ws += (size_t)(N_ITEMS + 1) * 4;
    int*   ecur   = (int*)ws;    ws += (size_t)N_ITEMS * 4;
    int*   epack  = (int*)ws;    ws += (size_t)N_EDGES * 4;
    int*   uoff   = (int*)ws;    ws += (size_t)(N_USERS + 1) * 4;
    int*   ucur   = (int*)ws;    ws += (size_t)N_USERS * 4;
    int*   ucol   = (int*)ws;    ws += (size_t)NNZ * 4;
    float* uval   = (float*)ws;  ws += (size_t)NNZ * 4;
    int*   ebsum  = (int*)ws;    ws += 256 * 4;
    int*   ubsum  = (int*)ws;    ws += 256 * 4;
    float* dis    = (float*)ws;  ws += 256 * 4;

    const int GE = (N_ITEMS + 1023) / 1024;
    const int GU = (N_USERS + 1023) / 1024;

    hipMemcpyAsync(ent0,       entity_emb, (size_t)N_ITEMS * DD * 4, hipMemcpyDeviceToDevice, stream);
    hipMemcpyAsync(cur_usr,    user_emb,   (size_t)N_USERS * DD * 4, hipMemcpyDeviceToDevice, stream);
    hipMemcpyAsync(entity_res, entity_emb, (size_t)N_ITEMS * DD * 4, hipMemcpyDeviceToDevice, stream);
    hipMemcpyAsync(user_res,   user_emb,   (size_t)N_USERS * DD * 4, hipMemcpyDeviceToDevice, stream);
    hipMemsetAsync(ecur, 0, (size_t)N_ITEMS * 4, stream);
    hipMemsetAsync(ucur, 0, (size_t)N_USERS * 4, stream);

    cor_kernel<<<1, 256, 0, stream>>>(att, cor_out);
    dis_kernel<<<1, 256, 0, stream>>>(att, weight, dis);

    count_int_kernel<<<(N_EDGES + 255) / 256, 256, 0, stream>>>(eidx, ecur, N_EDGES);
    count_int_kernel<<<(NNZ + 255) / 256, 256, 0, stream>>>(irow, ucur, NNZ);

    scanA_kernel<<<GE, 256, 0, stream>>>(ecur, ebsum, N_ITEMS);
    scanB_kernel<<<1, 256, 0, stream>>>(ebsum, GE, eoff, N_ITEMS);
    scanC_kernel<<<GE, 256, 0, stream>>>(ecur, ebsum, eoff, N_ITEMS);

    scanA_kernel<<<GU, 256, 0, stream>>>(ucur, ubsum, N_USERS);
    scanB_kernel<<<1, 256, 0, stream>>>(ubsum, GU, uoff, N_USERS);
    scanC_kernel<<<GU, 256, 0, stream>>>(ucur, ubsum, uoff, N_USERS);

    place_e_kernel<<<(N_EDGES + 255) / 256, 256, 0, stream>>>(eidx, etype, ecur, epack);
    place_u_kernel<<<(NNZ + 255) / 256, 256, 0, stream>>>(irow, icol, ival, ucur, ucol, uval);

    float* entbuf[2] = { ent0, ent1 };
    for (int layer = 0; layer < 2; ++layer) {
        float* eIn  = entbuf[layer & 1];
        float* eOut = entbuf[(layer & 1) ^ 1];
        user_layer_kernel<<<N_USERS / 16, 256, 0, stream>>>(uoff, ucol, uval,
                                                            (const float4*)eIn,
                                                            (const float4*)latent,
                                                            (const float4*)dis,
                                                            (float4*)cur_usr,
                                                            (float4*)user_res);
        entity_layer_kernel<<<N_ITEMS / 16, 256, 0, stream>>>(eoff, epack,
                                                              (const float4*)eIn,
                                                              (const float4*)weight,
                                                              (float4*)eOut,
                                                              (float4*)entity_res);
    }
}